// Round 6
// baseline (161.485 us; speedup 1.0000x reference)
//
#include <hip/hip_runtime.h>

// Problem: B=65536, C=2, P=41, L=4 cross-entropy + boundary weights + connectivity
// loss = mean( ce * w + 0.001 * conn )
// Round 6: LDS-staged (zero redundant global requests, dense streaming) with
// NBATCH=8 -> 15.7 KB LDS -> 8 blocks/CU -> 32 waves/CU (vs round 3's 5 blocks/43%).
constexpr int B   = 65536;
constexpr int P   = 41;
constexpr int PL  = P * 4;          // 164 elems per (b,c)
constexpr int CPL = 2 * PL;         // 328 logits floats per batch

constexpr int NBATCH = 8;                    // batches per block
constexpr int NBLK   = B / NBATCH;           // 8192 blocks
constexpr int NLOG4  = NBATCH * (CPL / 4);   // 656 float4 of logits per block
constexpr int NTGT4  = NBATCH * (PL  / 4);   // 328 int4 of targets per block
constexpr int NPAIR  = NBATCH * P;           // 328 (b,p) pairs per block

constexpr float INV_N = 1.0f / (float)(B * P * 4);
constexpr float CW    = 0.001f;
// GAMMA = 1.0 -> alpha = 1.0, beta = 0.5

__device__ __forceinline__ float pair_loss(const float4& a0, const float4& a1,
                                           const int4& tc,
                                           int xm1i, int xp1i, int xm2i, int xp2i,
                                           bool hm1, const float4& b0v, const float4& b1v)
{
    // per-lane weight bits come as packed int masks
    const float* A0 = (const float*)&a0;
    const float* A1 = (const float*)&a1;
    const float* B0 = (const float*)&b0v;
    const float* B1 = (const float*)&b1v;
    const int*   T  = (const int*)&tc;

    float sum = 0.0f;
    #pragma unroll
    for (int l = 0; l < 4; ++l) {
        float d  = A1[l] - A0[l];
        float g  = __logf(1.0f + __expf(-fabsf(d)));
        float sd = T[l] ? -d : d;                 // l_other - l_target
        float ce = fmaxf(sd, 0.0f) + g;
        float w  = 1.0f
                 + (float)(((xm1i >> l) & 1) + ((xp1i >> l) & 1))
                 + 0.5f * (float)(((xm2i >> l) & 1) + ((xp2i >> l) & 1));
        sum += ce * w;
        if (hm1) {
            bool pred  = (A1[l] > A0[l]);
            bool predm = (B1[l] > B0[l]);
            if (pred != predm) sum += CW;
        }
    }
    return sum;
}

__device__ __forceinline__ int pack_tgt(const int4& v) {
    return (v.x & 1) | ((v.y & 1) << 1) | ((v.z & 1) << 2) | ((v.w & 1) << 3);
}

__global__ __launch_bounds__(256)
void lace_partial_kernel(const float4* __restrict__ lg4,
                         const int4*   __restrict__ tg4,
                         float*        __restrict__ partial)
{
    __shared__ float4 s_log[NLOG4];   // [lb*82 + c*41 + p], 10496 B
    __shared__ int4   s_tgt[NTGT4];   // [lb*41 + p],         5248 B
    __shared__ float  wsum[4];

    const int tid = threadIdx.x;
    const int b0  = blockIdx.x * NBATCH;

    // ---- stage: contiguous, fully coalesced, each global byte requested once ----
    const float4* gsrc = lg4 + (size_t)b0 * (CPL / 4);
    const int4*   tsrc = tg4 + (size_t)b0 * (PL / 4);

    {
        int i0 = tid, i1 = tid + 256, i2 = tid + 512;
        s_log[i0] = gsrc[i0];
        s_log[i1] = gsrc[i1];
        if (i2 < NLOG4) s_log[i2] = gsrc[i2];          // 656 = 2*256 + 144
        s_tgt[i0] = tsrc[i0] , (void)0;                // wait: i0 may exceed? 256<328 ok
        if (i1 < NTGT4) s_tgt[i1] = tsrc[i1];          // 328 = 256 + 72
    }
    __syncthreads();

    // ---- compute: 328 pairs (pass 0: all 256 threads, pass 1: first 72) ----
    float sum = 0.0f;

    #pragma unroll
    for (int pass = 0; pass < 2; ++pass) {
        int pid = tid + pass * 256;
        if (pid < NPAIR) {
            int lb = pid / 41;               // magic-mul
            int p  = pid - lb * 41;

            int lbase = lb * 82 + p;         // float4 idx, c=0
            int tbase = pid;                 // lb*41 + p

            float4 a0 = s_log[lbase];        // logits[b,0,p,:]
            float4 a1 = s_log[lbase + 41];   // logits[b,1,p,:]
            int4   tc = s_tgt[tbase];

            bool hm1 = (p >= 1), hp1 = (p <= P - 2);
            bool hm2 = (p >= 2), hp2 = (p <= P - 3);

            float4 b0v = {0,0,0,0}, b1v = {0,0,0,0};
            int tm1 = 0, tp1 = 0, tm2 = 0, tp2 = 0;
            if (hm1) { tm1 = pack_tgt(s_tgt[tbase - 1]); b0v = s_log[lbase - 1]; b1v = s_log[lbase + 40]; }
            if (hp1) { tp1 = pack_tgt(s_tgt[tbase + 1]); }
            if (hm2) { tm2 = pack_tgt(s_tgt[tbase - 2]); }
            if (hp2) { tp2 = pack_tgt(s_tgt[tbase + 2]); }

            int tp = pack_tgt(tc);
            int xm1 = hm1 ? (tp ^ tm1) & 0xF : 0;
            int xp1 = hp1 ? (tp ^ tp1) & 0xF : 0;
            int xm2 = hm2 ? (tp ^ tm2) & 0xF : 0;
            int xp2 = hp2 ? (tp ^ tp2) & 0xF : 0;

            sum += pair_loss(a0, a1, tc, xm1, xp1, xm2, xp2, hm1, b0v, b1v);
        }
    }

    // ---- block reduction -> one partial per block ----
    #pragma unroll
    for (int off = 32; off > 0; off >>= 1)
        sum += __shfl_down(sum, off, 64);

    const int lane = tid & 63;
    const int wid  = tid >> 6;
    if (lane == 0) wsum[wid] = sum;
    __syncthreads();
    if (tid == 0)
        partial[blockIdx.x] = wsum[0] + wsum[1] + wsum[2] + wsum[3];
}

__global__ __launch_bounds__(1024)
void lace_reduce_kernel(const float* __restrict__ partial,
                        float*       __restrict__ out)
{
    // NBLK = 8192 = 8 * 1024 exactly
    float s = 0.0f;
    #pragma unroll
    for (int i = 0; i < 8; ++i)
        s += partial[threadIdx.x + i * 1024];

    #pragma unroll
    for (int off = 32; off > 0; off >>= 1)
        s += __shfl_down(s, off, 64);

    __shared__ float wsum[16];
    const int lane = threadIdx.x & 63;
    const int wid  = threadIdx.x >> 6;
    if (lane == 0) wsum[wid] = s;
    __syncthreads();
    if (threadIdx.x == 0) {
        float total = 0.0f;
        #pragma unroll
        for (int i = 0; i < 16; ++i) total += wsum[i];
        out[0] = total * INV_N;
    }
}

extern "C" void kernel_launch(void* const* d_in, const int* in_sizes, int n_in,
                              void* d_out, int out_size, void* d_ws, size_t ws_size,
                              hipStream_t stream) {
    const float4* lg4 = (const float4*)d_in[0];
    const int4*   tg4 = (const int4*)d_in[1];
    float* out     = (float*)d_out;
    float* partial = (float*)d_ws;   // 8192 floats

    lace_partial_kernel<<<NBLK, 256, 0, stream>>>(lg4, tg4, partial);
    lace_reduce_kernel<<<1, 1024, 0, stream>>>(partial, out);
}

// Round 7
// 155.838 us; speedup vs baseline: 1.0362x; 1.0362x over previous
//
#include <hip/hip_runtime.h>

// B=65536, C=2, P=41, L=4: loss = mean( ce*w + 0.001*conn )
//   ce   = relu(l_other - l_target) + log(1+exp(-|l1-l0|))
//   w    = 1 + |t[p]-t[p-1]| + |t[p+1]-t[p]| + 0.5(|t[p]-t[p-2]| + |t[p+2]-t[p]|), bounds-guarded
//   conn = (pred[p] != pred[p-1]), p>=1; pred = (l1 > l0)
//
// Round 7: branch-free. Boundary guards replaced by clamp-to-self neighbor
// indices: t XOR t = 0 reproduces the guard; self-pred makes conn=0 at p=0.
// All 9 loads unconditional & independent -> max MLP, zero exec-mask churn.
constexpr int B    = 65536;
constexpr int P    = 41;
constexpr int NTH  = B * P;          // 2,686,976 = 10,496 * 256 exactly (no tail)
constexpr int NBLK = NTH / 256;      // 10,496
constexpr float INV_N = 1.0f / (float)(B * P * 4);
constexpr float CW    = 0.001f;

__device__ __forceinline__ float comp1(float l0, float l1, float q0, float q1,
                                       int tx, int am1, int ap1, int am2, int ap2)
{
    float d  = l1 - l0;
    float g  = __logf(1.0f + __expf(-fabsf(d)));
    float ft = (float)tx;
    float sd = d * fmaf(-2.0f, ft, 1.0f);        // l_other - l_target
    float ce = fmaxf(sd, 0.0f) + g;

    int   x1 = (tx ^ am1) + (tx ^ ap1);          // 0..2
    int   x2 = (tx ^ am2) + (tx ^ ap2);          // 0..2
    float w  = fmaf(0.5f, (float)x2, 1.0f + (float)x1);

    float dm   = q1 - q0;                        // prev-p logit diff (self at p=0)
    float conn = ((d > 0.0f) != (dm > 0.0f)) ? CW : 0.0f;
    return fmaf(ce, w, conn);
}

__global__ __launch_bounds__(256)
void lace_partial_kernel(const float4* __restrict__ lg4,
                         const int4*   __restrict__ tg4,
                         float*        __restrict__ partial)
{
    const int t = blockIdx.x * 256 + threadIdx.x;   // (b,p) pair id, no tail
    const int b = t / P;                             // magic-mul
    const int p = t - b * P;

    // clamped-to-self neighbor positions (reproduce bounds guards exactly)
    const int pm1 = (p >= 1) ? p - 1 : p;            // max(p-1,0)
    const int pp1 = (p <= P - 2) ? p + 1 : p;        // min(p+1,40)
    const int pm2 = (p >= 2) ? p - 2 : p;            // NOTE: p=1 -> self, not 0
    const int pp2 = (p <= P - 3) ? p + 2 : p;

    const int f4 = b * 82 + p;                       // float4 idx of logits[b,0,p,:]
    const int fm = b * 82 + pm1;
    const int tb = t - p;                            // b*41

    // ---- 9 unconditional, independent loads ----
    float4 a0 = lg4[f4];
    float4 a1 = lg4[f4 + 41];
    float4 q0 = lg4[fm];
    float4 q1 = lg4[fm + 41];
    int4   tc = tg4[t];
    int4   nA = tg4[tb + pm1];
    int4   nB = tg4[tb + pp1];
    int4   nC = tg4[tb + pm2];
    int4   nD = tg4[tb + pp2];

    float sum = comp1(a0.x, a1.x, q0.x, q1.x, tc.x, nA.x, nB.x, nC.x, nD.x)
              + comp1(a0.y, a1.y, q0.y, q1.y, tc.y, nA.y, nB.y, nC.y, nD.y)
              + comp1(a0.z, a1.z, q0.z, q1.z, tc.z, nA.z, nB.z, nC.z, nD.z)
              + comp1(a0.w, a1.w, q0.w, q1.w, tc.w, nA.w, nB.w, nC.w, nD.w);

    // ---- block reduction -> one partial per block ----
    #pragma unroll
    for (int off = 32; off > 0; off >>= 1)
        sum += __shfl_down(sum, off, 64);

    __shared__ float wsum[4];
    const int lane = threadIdx.x & 63;
    const int wid  = threadIdx.x >> 6;
    if (lane == 0) wsum[wid] = sum;
    __syncthreads();
    if (threadIdx.x == 0)
        partial[blockIdx.x] = wsum[0] + wsum[1] + wsum[2] + wsum[3];
}

__global__ __launch_bounds__(1024)
void lace_reduce_kernel(const float* __restrict__ partial,
                        float*       __restrict__ out)
{
    float s = 0.0f;
    for (int i = threadIdx.x; i < NBLK; i += 1024)
        s += partial[i];

    #pragma unroll
    for (int off = 32; off > 0; off >>= 1)
        s += __shfl_down(s, off, 64);

    __shared__ float wsum[16];
    const int lane = threadIdx.x & 63;
    const int wid  = threadIdx.x >> 6;
    if (lane == 0) wsum[wid] = s;
    __syncthreads();
    if (threadIdx.x == 0) {
        float total = 0.0f;
        #pragma unroll
        for (int i = 0; i < 16; ++i) total += wsum[i];
        out[0] = total * INV_N;
    }
}

extern "C" void kernel_launch(void* const* d_in, const int* in_sizes, int n_in,
                              void* d_out, int out_size, void* d_ws, size_t ws_size,
                              hipStream_t stream) {
    const float4* lg4 = (const float4*)d_in[0];
    const int4*   tg4 = (const int4*)d_in[1];
    float* out     = (float*)d_out;
    float* partial = (float*)d_ws;   // 10,496 floats

    lace_partial_kernel<<<NBLK, 256, 0, stream>>>(lg4, tg4, partial);
    lace_reduce_kernel<<<1, 1024, 0, stream>>>(partial, out);
}